// Round 4
// baseline (469.232 us; speedup 1.0000x reference)
//
#include <hip/hip_runtime.h>

// GCNConv: out = D^-1/2 (A) D^-1/2 (X @ W) + bias,  deg = rowsum(A) + l
// N=8192, DIN=DOUT=256. A fp32 [N][N], X fp32 [N][256], W fp32 [256][256].
//
// R8 resubmit (container infra failure; kernel re-audited, unchanged):
// k4 occupancy experiment, one variable: 8 -> 16 waves/CU.
//  * Same BM=64/BN=256/BK=64 tile, same 4-deep LDS ring + reg-B pipeline,
//    but 512-thread blocks with a 64x32 per-wave tile: acc 64->32 VGPR,
//    B-regs 64->32 -> fits 128-VGPR cap (__launch_bounds__(512,4)) ->
//    2 blocks/CU = 16 waves/CU, doubling in-flight loads (Little's law).
//  * Per-CU per-iter traffic and MFMA work UNCHANGED -> isolates the
//    concurrency variable. A-stage = exactly 1 global_load_lds per thread;
//    B = 4 BLOADs/wave; steady-state wait vmcnt(5) (= A(it+1)x1 + B(it+1)x4).
// Workspace: 32KB d | 128KB WT | 4MB ST | 32MB partials | 128MB A_bf16.

typedef __attribute__((ext_vector_type(8))) short short8;
typedef __attribute__((ext_vector_type(4))) float f32x4;

#define NN 8192
#define DD 256
#define KCHUNK 2048
#define BK 64
#define NITER (KCHUNK / BK)

// fp32 -> bf16 RNE (no NaN guard: inputs are finite)
__device__ inline unsigned short f2bfu(float x) {
    unsigned int u = __builtin_bit_cast(unsigned int, x);
    u += 0x7fffu + ((u >> 16) & 1u);
    return (unsigned short)(u >> 16);
}
__device__ inline unsigned int f2bf2u(float x, float y) {
    return (unsigned int)f2bfu(x) | ((unsigned int)f2bfu(y) << 16);
}
__device__ inline short8 cvt8(float4 a, float4 b) {
    union { unsigned int i[4]; short8 s; } u;
    u.i[0] = f2bf2u(a.x, a.y);
    u.i[1] = f2bf2u(a.z, a.w);
    u.i[2] = f2bf2u(b.x, b.y);
    u.i[3] = f2bf2u(b.z, b.w);
    return u.s;
}

__device__ inline void gload16(const void* g, void* l) {
    __builtin_amdgcn_global_load_lds(
        (const __attribute__((address_space(1))) unsigned int*)g,
        (__attribute__((address_space(3))) unsigned int*)l, 16, 0, 0);
}

// asm global load: invisible to LLVM's waitcnt pass; retired only by our
// hand-placed s_waitcnt vmcnt(N).
#define BLOAD(dst, ptr, OFFSTR)                                        \
    asm volatile("global_load_dwordx4 %0, %1, off offset:" OFFSTR      \
                 : "=v"(dst) : "v"(ptr))

// ---------------- k1: rowsum -> d[i]; A -> bf16 swizzled tile image --------
__global__ __launch_bounds__(256) void rowsum_conv(const float* __restrict__ A,
                                                   const int* __restrict__ lp,
                                                   float* __restrict__ d,
                                                   unsigned short* __restrict__ Abf) {
    const int t = threadIdx.x;
    const int rl = t >> 4;     // row within block
    const int cg = t & 15;     // 16 threads per row
    const int i = blockIdx.x * 16 + rl;
    const int ti = i >> 6;
    const int rt = i & 63;
    const int swz = (rt & 7) << 4;

    const f32x4* Ar = (const f32x4*)(A + (size_t)i * NN);
    char* tb = (char*)Abf + (size_t)ti * 128 * 8192 + rt * 128 + ((8 * cg) ^ swz);

    float s0 = 0.f, s1 = 0.f;
#pragma unroll 4
    for (int k = 0; k < 128; ++k) {
        f32x4 v = __builtin_nontemporal_load(Ar + cg + 16 * k);  // nt: keep L3 for Abf
        s0 += v[0] + v[1];
        s1 += v[2] + v[3];
        *(uint2*)(tb + (size_t)k * 8192) =
            make_uint2(f2bf2u(v[0], v[1]), f2bf2u(v[2], v[3]));
    }
    float s = s0 + s1;
#pragma unroll
    for (int off = 8; off > 0; off >>= 1) s += __shfl_down(s, off, 16);
    if (cg == 0) {
        float deg = s + (float)(*lp);
        d[i] = deg > 0.f ? rsqrtf(deg) : 0.f;
    }
}

// ---------------- k2: W^T -> bf16 ----------------------------------------
__global__ __launch_bounds__(256) void wtrans_kernel(const float* __restrict__ W,
                                                     unsigned short* __restrict__ WT) {
    __shared__ unsigned short tile[64][65];
    const int tx = threadIdx.x & 63, ty = threadIdx.x >> 6;
    const int i0 = (blockIdx.x & 3) * 64;
    const int n0 = (blockIdx.x >> 2) * 64;
#pragma unroll
    for (int r = ty; r < 64; r += 4)
        tile[r][tx] = f2bfu(W[(size_t)(i0 + r) * DD + n0 + tx]);
    __syncthreads();
#pragma unroll
    for (int r = ty; r < 64; r += 4)
        WT[(size_t)(n0 + r) * DD + i0 + tx] = tile[tx][r];
}

// ---------------- k3: S_T[n][j] = bf16(d_j * (X@W)[j][n]) ----------------
__global__ __launch_bounds__(256) void support_kernel(const float* __restrict__ X,
                                                      const unsigned short* __restrict__ WT,
                                                      const float* __restrict__ d,
                                                      unsigned short* __restrict__ ST) {
    const int j0 = blockIdx.x * 16;
    const int lane = threadIdx.x & 63;
    const int w = threadIdx.x >> 6;
    const int q = lane >> 4;
    const int l15 = lane & 15;
    const int nb = w * 64;

    f32x4 acc[4];
#pragma unroll
    for (int b = 0; b < 4; ++b) acc[b] = (f32x4)(0.f);

    const float* Xbase = X + (size_t)(j0 + l15) * DD + q * 8;
    const unsigned short* Wbase = WT + (size_t)(nb + l15) * DD + q * 8;

#pragma unroll
    for (int k0 = 0; k0 < DD; k0 += 32) {
        const float4* p = (const float4*)(Xbase + k0);
        short8 afr = cvt8(p[0], p[1]);
        short8 bfr[4];
#pragma unroll
        for (int ni = 0; ni < 4; ++ni)
            bfr[ni] = *(const short8*)(Wbase + ni * 16 * DD + k0);
#pragma unroll
        for (int ni = 0; ni < 4; ++ni)
            acc[ni] = __builtin_amdgcn_mfma_f32_16x16x32_bf16(afr, bfr[ni], acc[ni], 0, 0, 0);
    }

    const int j0r = j0 + q * 4;
    float dj[4];
#pragma unroll
    for (int r = 0; r < 4; ++r) dj[r] = d[j0r + r];
#pragma unroll
    for (int ni = 0; ni < 4; ++ni) {
        const int n = nb + ni * 16 + l15;
        unsigned int lo = f2bf2u(acc[ni][0] * dj[0], acc[ni][1] * dj[1]);
        unsigned int hi = f2bf2u(acc[ni][2] * dj[2], acc[ni][3] * dj[3]);
        *(uint2*)(ST + (size_t)n * NN + j0r) = make_uint2(lo, hi);
    }
}

// ---------------- k4: partial[kc] = A_bf16 @ S_T^T -----------------------
// BM=64, BN=256, BK=64, KCHUNK=2048; 512 blocks x 512 thr (2/CU, 16 w/CU).
// Per-wave tile 64x32 (acc 32 VGPR). Per iter: [vmcnt(5); s_barrier] |
// issue A(it+2)->ring (1 gload_lds/thread) | compute(it) from LDS[it&3] +
// bfr[it&1] | issue B(it+2) into slot it&1 (WAR-safe: after its MFMAs).
// vmcnt(5) keeps {A(it+1)x1, B(it+1)x4} in flight; never drains.
__global__ __launch_bounds__(512, 4) void main_gemm(const unsigned short* __restrict__ Abf,
                                                    const unsigned short* __restrict__ ST,
                                                    float* __restrict__ part) {
    __shared__ __align__(16) unsigned short Abuf[4][4096];  // 4-deep ring, 32 KB

    const int bid = blockIdx.x;
    // XCD swizzle: bid%8 == XCD; 2 XCDs per kc -> 1 MB B-slice per L2.
    const int kc = (bid & 7) >> 1;                 // 0..3
    const int mt = ((bid >> 3) << 1) | (bid & 1);  // 0..127
    const int tid = threadIdx.x;                   // 0..511
    const int lane = tid & 63;
    const int w = tid >> 6;                        // 0..7
    const int q = lane >> 4;
    const int l15 = lane & 15;
    const int swz = (l15 & 7) << 4;

    // A image source: one 16B gload_lds per thread covers the 8 KB tile
    const char* Ag = (const char*)Abf + ((size_t)mt * 128 + kc * NITER) * 8192 + tid * 16;

    // per-ni B base pointers (wave covers n in [w*32, w*32+32))
    const char* Pn[2];
#pragma unroll
    for (int ni = 0; ni < 2; ++ni)
        Pn[ni] = (const char*)ST +
                 ((size_t)(w * 32 + ni * 16 + l15) * NN + (size_t)kc * KCHUNK + q * 8) * 2;

    f32x4 acc[4][2];
#pragma unroll
    for (int a = 0; a < 4; ++a)
#pragma unroll
        for (int b = 0; b < 2; ++b) acc[a][b] = (f32x4)(0.f);

    short8 bfr[2][2][2];  // [slot][kk2][ni]

    // ---- prologue: A0, B0, A1, B1 (issue order is the vmcnt contract)
    gload16(Ag, (char*)&Abuf[0][0] + tid * 16);
    __builtin_amdgcn_sched_barrier(0);
#pragma unroll
    for (int ni = 0; ni < 2; ++ni) {
        BLOAD(bfr[0][0][ni], Pn[ni], "0");
        BLOAD(bfr[0][1][ni], Pn[ni], "64");
    }
    __builtin_amdgcn_sched_barrier(0);
    gload16(Ag + 8192, (char*)&Abuf[1][0] + tid * 16);
    __builtin_amdgcn_sched_barrier(0);
#pragma unroll
    for (int ni = 0; ni < 2; ++ni) {
        BLOAD(bfr[1][0][ni], Pn[ni], "128");
        BLOAD(bfr[1][1][ni], Pn[ni], "192");
    }
    __builtin_amdgcn_sched_barrier(0);

    const char* AbBase = (const char*)&Abuf[0][0] + l15 * 128;

#pragma unroll 2
    for (int it = 0; it < NITER - 2; ++it) {
        // retire A(it)+B(it); keep A(it+1)x1 + B(it+1)x4 in flight
        __asm__ __volatile__("s_waitcnt vmcnt(5)\n\ts_barrier" ::: "memory");
        __builtin_amdgcn_sched_barrier(0);

        // issue A(it+2) into ring slot (it+2)&3
        gload16(Ag + (size_t)(it + 2) * 8192,
                (char*)&Abuf[0][0] + (((it + 2) & 3) << 13) + tid * 16);
        __builtin_amdgcn_sched_barrier(0);

        // compute(it): swizzled ds_read_b128 frags + register B slot it&1
        const char* Ab = AbBase + ((it & 3) << 13);
#pragma unroll
        for (int kk2 = 0; kk2 < 2; ++kk2) {
            short8 afr[4];
#pragma unroll
            for (int mi = 0; mi < 4; ++mi)
                afr[mi] = *(const short8*)(Ab + mi * 2048 + ((kk2 * 64 + q * 16) ^ swz));
#pragma unroll
            for (int mi = 0; mi < 4; ++mi)
#pragma unroll
                for (int ni = 0; ni < 2; ++ni)
                    acc[mi][ni] = __builtin_amdgcn_mfma_f32_16x16x32_bf16(
                        afr[mi], bfr[it & 1][kk2][ni], acc[mi][ni], 0, 0, 0);
        }
        __builtin_amdgcn_sched_barrier(0);

        // issue B(it+2) into slot it&1 (all consuming MFMAs already issued)
#pragma unroll
        for (int ni = 0; ni < 2; ++ni) {
            BLOAD(bfr[it & 1][0][ni], Pn[ni], "256");
            BLOAD(bfr[it & 1][1][ni], Pn[ni], "320");
        }
#pragma unroll
        for (int ni = 0; ni < 2; ++ni) Pn[ni] += 128;
        __builtin_amdgcn_sched_barrier(0);
    }

    // ---- peel it = NITER-2 (ring 2, slot 0)
    __asm__ __volatile__("s_waitcnt vmcnt(5)\n\ts_barrier" ::: "memory");
    __builtin_amdgcn_sched_barrier(0);
    {
        const char* Ab = AbBase + (((NITER - 2) & 3) << 13);
#pragma unroll
        for (int kk2 = 0; kk2 < 2; ++kk2) {
            short8 afr[4];
#pragma unroll
            for (int mi = 0; mi < 4; ++mi)
                afr[mi] = *(const short8*)(Ab + mi * 2048 + ((kk2 * 64 + q * 16) ^ swz));
#pragma unroll
            for (int mi = 0; mi < 4; ++mi)
#pragma unroll
                for (int ni = 0; ni < 2; ++ni)
                    acc[mi][ni] = __builtin_amdgcn_mfma_f32_16x16x32_bf16(
                        afr[mi], bfr[0][kk2][ni], acc[mi][ni], 0, 0, 0);
        }
    }
    // ---- peel it = NITER-1 (ring 3, slot 1)
    __asm__ __volatile__("s_waitcnt vmcnt(0)\n\ts_barrier" ::: "memory");
    __builtin_amdgcn_sched_barrier(0);
    {
        const char* Ab = AbBase + (((NITER - 1) & 3) << 13);
#pragma unroll
        for (int kk2 = 0; kk2 < 2; ++kk2) {
            short8 afr[4];
#pragma unroll
            for (int mi = 0; mi < 4; ++mi)
                afr[mi] = *(const short8*)(Ab + mi * 2048 + ((kk2 * 64 + q * 16) ^ swz));
#pragma unroll
            for (int mi = 0; mi < 4; ++mi)
#pragma unroll
                for (int ni = 0; ni < 2; ++ni)
                    acc[mi][ni] = __builtin_amdgcn_mfma_f32_16x16x32_bf16(
                        afr[mi], bfr[1][kk2][ni], acc[mi][ni], 0, 0, 0);
        }
    }

    // epilogue: plain stores of raw partials (d_i & bias applied in reduce)
    float* P = part + (size_t)kc * NN * DD;
#pragma unroll
    for (int mi = 0; mi < 4; ++mi) {
        const int r0 = mt * 64 + mi * 16 + q * 4;
#pragma unroll
        for (int ni = 0; ni < 2; ++ni) {
            const int n = w * 32 + ni * 16 + l15;
#pragma unroll
            for (int rr = 0; rr < 4; ++rr)
                P[(size_t)(r0 + rr) * DD + n] = acc[mi][ni][rr];
        }
    }
}

// ---------------- k5: out = d_i * (p0+p1+p2+p3) + bias -------------------
__global__ __launch_bounds__(256) void reduce_kernel(const float* __restrict__ part,
                                                     const float* __restrict__ d,
                                                     const float* __restrict__ bias,
                                                     float* __restrict__ out) {
    const int idx = blockIdx.x * 256 + threadIdx.x;  // 0..524287
    const int i = idx >> 6;                          // row
    const int c4 = (idx & 63) << 2;                  // col (floats)
    const size_t off = (size_t)i * DD + c4;
    const size_t stride = (size_t)NN * DD;
    f32x4 s = *(const f32x4*)(part + off);
    s += *(const f32x4*)(part + stride + off);
    s += *(const f32x4*)(part + 2 * stride + off);
    s += *(const f32x4*)(part + 3 * stride + off);
    const float di = d[i];
    const f32x4 b = *(const f32x4*)(bias + c4);
    s = s * di + b;
    *(f32x4*)(out + off) = s;
}

extern "C" void kernel_launch(void* const* d_in, const int* in_sizes, int n_in,
                              void* d_out, int out_size, void* d_ws, size_t ws_size,
                              hipStream_t stream) {
    const float* A = (const float*)d_in[0];
    const float* X = (const float*)d_in[1];
    const float* W = (const float*)d_in[2];
    const float* bias = (const float*)d_in[3];
    const int* lp = (const int*)d_in[4];
    float* out = (float*)d_out;

    // workspace: d[8192] f32 | WT bf16[256*256] | ST bf16[256*8192] |
    //            part f32[4*8192*256] | Abf bf16[8192*8192]  (~164.2 MB)
    float* d = (float*)d_ws;
    unsigned short* WT = (unsigned short*)((char*)d_ws + 32768);
    unsigned short* ST = (unsigned short*)((char*)d_ws + 32768 + 131072);
    float* part = (float*)((char*)d_ws + 4358144);
    unsigned short* Abf = (unsigned short*)((char*)d_ws + 37912576);
    (void)ws_size;

    rowsum_conv<<<NN / 16, 256, 0, stream>>>(A, lp, d, Abf);
    wtrans_kernel<<<16, 256, 0, stream>>>(W, WT);
    support_kernel<<<NN / 16, 256, 0, stream>>>(X, WT, d, ST);
    main_gemm<<<128 * (NN / KCHUNK), 512, 0, stream>>>(Abf, ST, part);
    reduce_kernel<<<NN * DD / 4 / 256, 256, 0, stream>>>(part, d, bias, out);
}

// Round 5
// 446.072 us; speedup vs baseline: 1.0519x; 1.0519x over previous
//
#include <hip/hip_runtime.h>

// GCNConv: out = D^-1/2 (A) D^-1/2 (X @ W) + bias,  deg = rowsum(A) + l
// N=8192, DIN=DOUT=256. A fp32 [N][N], X fp32 [N][256], W fp32 [256][256].
//
// R8 -> R9 (one variable: B-operand L2 REQUEST GRANULARITY):
//  * ST re-laid out as a fragment-ordered tile image, written by k3:
//    ST_img[nblk32:8][ktile:128][kk2:2][ni:2][lane:64][16B]  (4 MB, same size).
//    k4's B loads become contiguous 1KB per instruction (lane*16) -> 8 full
//    128B-line L2 requests per load instead of 16 half-line requests.
//    Halves B request count; every fetched line 100% used on first touch.
//  * Everything else identical to R8: BM=64/BN=256/BK=64, 512 thr, 16 w/CU,
//    4-deep LDS ring via global_load_lds, vmcnt(5) steady-state, partials+k5.
// Workspace: 32KB d | 128KB WT | 4MB ST_img | 32MB partials | 128MB A_bf16.

typedef __attribute__((ext_vector_type(8))) short short8;
typedef __attribute__((ext_vector_type(4))) float f32x4;

#define NN 8192
#define DD 256
#define KCHUNK 2048
#define BK 64
#define NITER (KCHUNK / BK)

// fp32 -> bf16 RNE (no NaN guard: inputs are finite)
__device__ inline unsigned short f2bfu(float x) {
    unsigned int u = __builtin_bit_cast(unsigned int, x);
    u += 0x7fffu + ((u >> 16) & 1u);
    return (unsigned short)(u >> 16);
}
__device__ inline unsigned int f2bf2u(float x, float y) {
    return (unsigned int)f2bfu(x) | ((unsigned int)f2bfu(y) << 16);
}
__device__ inline short8 cvt8(float4 a, float4 b) {
    union { unsigned int i[4]; short8 s; } u;
    u.i[0] = f2bf2u(a.x, a.y);
    u.i[1] = f2bf2u(a.z, a.w);
    u.i[2] = f2bf2u(b.x, b.y);
    u.i[3] = f2bf2u(b.z, b.w);
    return u.s;
}

__device__ inline void gload16(const void* g, void* l) {
    __builtin_amdgcn_global_load_lds(
        (const __attribute__((address_space(1))) unsigned int*)g,
        (__attribute__((address_space(3))) unsigned int*)l, 16, 0, 0);
}

// asm global load: invisible to LLVM's waitcnt pass; retired only by our
// hand-placed s_waitcnt vmcnt(N).
#define BLOAD(dst, ptr, OFFSTR)                                        \
    asm volatile("global_load_dwordx4 %0, %1, off offset:" OFFSTR      \
                 : "=v"(dst) : "v"(ptr))

// ---------------- k1: rowsum -> d[i]; A -> bf16 swizzled tile image --------
__global__ __launch_bounds__(256) void rowsum_conv(const float* __restrict__ A,
                                                   const int* __restrict__ lp,
                                                   float* __restrict__ d,
                                                   unsigned short* __restrict__ Abf) {
    const int t = threadIdx.x;
    const int rl = t >> 4;     // row within block
    const int cg = t & 15;     // 16 threads per row
    const int i = blockIdx.x * 16 + rl;
    const int ti = i >> 6;
    const int rt = i & 63;
    const int swz = (rt & 7) << 4;

    const f32x4* Ar = (const f32x4*)(A + (size_t)i * NN);
    char* tb = (char*)Abf + (size_t)ti * 128 * 8192 + rt * 128 + ((8 * cg) ^ swz);

    float s0 = 0.f, s1 = 0.f;
#pragma unroll 4
    for (int k = 0; k < 128; ++k) {
        f32x4 v = __builtin_nontemporal_load(Ar + cg + 16 * k);  // nt: keep L3 for Abf
        s0 += v[0] + v[1];
        s1 += v[2] + v[3];
        *(uint2*)(tb + (size_t)k * 8192) =
            make_uint2(f2bf2u(v[0], v[1]), f2bf2u(v[2], v[3]));
    }
    float s = s0 + s1;
#pragma unroll
    for (int off = 8; off > 0; off >>= 1) s += __shfl_down(s, off, 16);
    if (cg == 0) {
        float deg = s + (float)(*lp);
        d[i] = deg > 0.f ? rsqrtf(deg) : 0.f;
    }
}

// ---------------- k2: W^T -> bf16 ----------------------------------------
__global__ __launch_bounds__(256) void wtrans_kernel(const float* __restrict__ W,
                                                     unsigned short* __restrict__ WT) {
    __shared__ unsigned short tile[64][65];
    const int tx = threadIdx.x & 63, ty = threadIdx.x >> 6;
    const int i0 = (blockIdx.x & 3) * 64;
    const int n0 = (blockIdx.x >> 2) * 64;
#pragma unroll
    for (int r = ty; r < 64; r += 4)
        tile[r][tx] = f2bfu(W[(size_t)(i0 + r) * DD + n0 + tx]);
    __syncthreads();
#pragma unroll
    for (int r = ty; r < 64; r += 4)
        WT[(size_t)(n0 + r) * DD + i0 + tx] = tile[tx][r];
}

// ---------------- k3: S_T image = bf16(d_j * (X@W)[j][n]) ----------------
// Output layout (fragment-ordered image, 4 MB):
//   byte = nblk32*524288 + ktile*4096 + kk2*2048 + ni*1024 + lane*16 + b
//   where n = nblk32*32 + ni*16 + (lane&15), k = ktile*64 + kk2*32 +
//   (lane>>4)*8 + b/2.  k4 reads it as 4 contiguous 1KB loads per wave-iter.
__global__ __launch_bounds__(256) void support_kernel(const float* __restrict__ X,
                                                      const unsigned short* __restrict__ WT,
                                                      const float* __restrict__ d,
                                                      unsigned short* __restrict__ ST) {
    const int j0 = blockIdx.x * 16;
    const int lane = threadIdx.x & 63;
    const int w = threadIdx.x >> 6;
    const int q = lane >> 4;
    const int l15 = lane & 15;
    const int nb = w * 64;

    f32x4 acc[4];
#pragma unroll
    for (int b = 0; b < 4; ++b) acc[b] = (f32x4)(0.f);

    const float* Xbase = X + (size_t)(j0 + l15) * DD + q * 8;
    const unsigned short* Wbase = WT + (size_t)(nb + l15) * DD + q * 8;

#pragma unroll
    for (int k0 = 0; k0 < DD; k0 += 32) {
        const float4* p = (const float4*)(Xbase + k0);
        short8 afr = cvt8(p[0], p[1]);
        short8 bfr[4];
#pragma unroll
        for (int ni = 0; ni < 4; ++ni)
            bfr[ni] = *(const short8*)(Wbase + ni * 16 * DD + k0);
#pragma unroll
        for (int ni = 0; ni < 4; ++ni)
            acc[ni] = __builtin_amdgcn_mfma_f32_16x16x32_bf16(afr, bfr[ni], acc[ni], 0, 0, 0);
    }

    const int j0r = j0 + q * 4;   // 4 consecutive k's, j0r % 4 == 0
    float dj[4];
#pragma unroll
    for (int r = 0; r < 4; ++r) dj[r] = d[j0r + r];
    // image coords from k-position (same for all ni)
    const int ktile = j0r >> 6;
    const int kk2i = (j0r >> 5) & 1;
    const int qi = (j0r >> 3) & 3;
    const int bo = (j0r & 7) * 2;  // 0 or 8
#pragma unroll
    for (int ni = 0; ni < 4; ++ni) {
        const int n = nb + ni * 16 + l15;
        unsigned int lo = f2bf2u(acc[ni][0] * dj[0], acc[ni][1] * dj[1]);
        unsigned int hi = f2bf2u(acc[ni][2] * dj[2], acc[ni][3] * dj[3]);
        char* dst = (char*)ST + (size_t)(n >> 5) * 524288 + ktile * 4096 +
                    kk2i * 2048 + ((n >> 4) & 1) * 1024 + (qi * 16 + (n & 15)) * 16 + bo;
        *(uint2*)dst = make_uint2(lo, hi);
    }
}

// ---------------- k4: partial[kc] = A_bf16 @ S_img^T ---------------------
// BM=64, BN=256, BK=64, KCHUNK=2048; 512 blocks x 512 thr (2/CU, 16 w/CU).
// Per iter: [vmcnt(5); s_barrier] | issue A(it+2)->ring (1 gload_lds/thr) |
// compute(it) from LDS[it&3] + bfr[it&1] | issue B(it+2) as 4 contiguous
// 1KB loads into slot it&1. vmcnt(5) keeps {A(it+1)x1, B(it+1)x4} in flight.
__global__ __launch_bounds__(512, 4) void main_gemm(const unsigned short* __restrict__ Abf,
                                                    const unsigned short* __restrict__ ST,
                                                    float* __restrict__ part) {
    __shared__ __align__(16) unsigned short Abuf[4][4096];  // 4-deep ring, 32 KB

    const int bid = blockIdx.x;
    // XCD swizzle: bid%8 == XCD; 2 XCDs per kc -> 1 MB B-slice per L2.
    const int kc = (bid & 7) >> 1;                 // 0..3
    const int mt = ((bid >> 3) << 1) | (bid & 1);  // 0..127
    const int tid = threadIdx.x;                   // 0..511
    const int lane = tid & 63;
    const int w = tid >> 6;                        // 0..7
    const int q = lane >> 4;
    const int l15 = lane & 15;
    const int swz = (l15 & 7) << 4;

    // A image source: one 16B gload_lds per thread covers the 8 KB tile
    const char* Ag = (const char*)Abf + ((size_t)mt * 128 + kc * NITER) * 8192 + tid * 16;

    // B image: wave w owns nblk32 = w; tile (kc*32 + it) at 4 KB stride.
    // 4 contiguous 1KB loads per iter at offsets 0/1024/2048/3072.
    const char* Pb = (const char*)ST + (size_t)w * 524288 + (size_t)kc * 32 * 4096 + lane * 16;

    f32x4 acc[4][2];
#pragma unroll
    for (int a = 0; a < 4; ++a)
#pragma unroll
        for (int b = 0; b < 2; ++b) acc[a][b] = (f32x4)(0.f);

    short8 bfr[2][2][2];  // [slot][kk2][ni]

    // ---- prologue: A0, B0, A1, B1 (issue order is the vmcnt contract)
    gload16(Ag, (char*)&Abuf[0][0] + tid * 16);
    __builtin_amdgcn_sched_barrier(0);
    BLOAD(bfr[0][0][0], Pb, "0");
    BLOAD(bfr[0][0][1], Pb, "1024");
    BLOAD(bfr[0][1][0], Pb, "2048");
    BLOAD(bfr[0][1][1], Pb, "3072");
    __builtin_amdgcn_sched_barrier(0);
    gload16(Ag + 8192, (char*)&Abuf[1][0] + tid * 16);
    __builtin_amdgcn_sched_barrier(0);
    {
        const char* Pb1 = Pb + 4096;
        BLOAD(bfr[1][0][0], Pb1, "0");
        BLOAD(bfr[1][0][1], Pb1, "1024");
        BLOAD(bfr[1][1][0], Pb1, "2048");
        BLOAD(bfr[1][1][1], Pb1, "3072");
    }
    __builtin_amdgcn_sched_barrier(0);

    const char* AbBase = (const char*)&Abuf[0][0] + l15 * 128;
    const char* PbN = Pb + 8192;  // points at tile (it+2)

#pragma unroll 2
    for (int it = 0; it < NITER - 2; ++it) {
        // retire A(it)+B(it); keep A(it+1)x1 + B(it+1)x4 in flight
        __asm__ __volatile__("s_waitcnt vmcnt(5)\n\ts_barrier" ::: "memory");
        __builtin_amdgcn_sched_barrier(0);

        // issue A(it+2) into ring slot (it+2)&3
        gload16(Ag + (size_t)(it + 2) * 8192,
                (char*)&Abuf[0][0] + (((it + 2) & 3) << 13) + tid * 16);
        __builtin_amdgcn_sched_barrier(0);

        // compute(it): swizzled ds_read_b128 frags + register B slot it&1
        const char* Ab = AbBase + ((it & 3) << 13);
#pragma unroll
        for (int kk2 = 0; kk2 < 2; ++kk2) {
            short8 afr[4];
#pragma unroll
            for (int mi = 0; mi < 4; ++mi)
                afr[mi] = *(const short8*)(Ab + mi * 2048 + ((kk2 * 64 + q * 16) ^ swz));
#pragma unroll
            for (int mi = 0; mi < 4; ++mi)
#pragma unroll
                for (int ni = 0; ni < 2; ++ni)
                    acc[mi][ni] = __builtin_amdgcn_mfma_f32_16x16x32_bf16(
                        afr[mi], bfr[it & 1][kk2][ni], acc[mi][ni], 0, 0, 0);
        }
        __builtin_amdgcn_sched_barrier(0);

        // issue B(it+2) into slot it&1 (all consuming MFMAs already issued)
        BLOAD(bfr[it & 1][0][0], PbN, "0");
        BLOAD(bfr[it & 1][0][1], PbN, "1024");
        BLOAD(bfr[it & 1][1][0], PbN, "2048");
        BLOAD(bfr[it & 1][1][1], PbN, "3072");
        PbN += 4096;
        __builtin_amdgcn_sched_barrier(0);
    }

    // ---- peel it = NITER-2 (ring 2, slot 0)
    __asm__ __volatile__("s_waitcnt vmcnt(5)\n\ts_barrier" ::: "memory");
    __builtin_amdgcn_sched_barrier(0);
    {
        const char* Ab = AbBase + (((NITER - 2) & 3) << 13);
#pragma unroll
        for (int kk2 = 0; kk2 < 2; ++kk2) {
            short8 afr[4];
#pragma unroll
            for (int mi = 0; mi < 4; ++mi)
                afr[mi] = *(const short8*)(Ab + mi * 2048 + ((kk2 * 64 + q * 16) ^ swz));
#pragma unroll
            for (int mi = 0; mi < 4; ++mi)
#pragma unroll
                for (int ni = 0; ni < 2; ++ni)
                    acc[mi][ni] = __builtin_amdgcn_mfma_f32_16x16x32_bf16(
                        afr[mi], bfr[0][kk2][ni], acc[mi][ni], 0, 0, 0);
        }
    }
    // ---- peel it = NITER-1 (ring 3, slot 1)
    __asm__ __volatile__("s_waitcnt vmcnt(0)\n\ts_barrier" ::: "memory");
    __builtin_amdgcn_sched_barrier(0);
    {
        const char* Ab = AbBase + (((NITER - 1) & 3) << 13);
#pragma unroll
        for (int kk2 = 0; kk2 < 2; ++kk2) {
            short8 afr[4];
#pragma unroll
            for (int mi = 0; mi < 4; ++mi)
                afr[mi] = *(const short8*)(Ab + mi * 2048 + ((kk2 * 64 + q * 16) ^ swz));
#pragma unroll
            for (int mi = 0; mi < 4; ++mi)
#pragma unroll
                for (int ni = 0; ni < 2; ++ni)
                    acc[mi][ni] = __builtin_amdgcn_mfma_f32_16x16x32_bf16(
                        afr[mi], bfr[1][kk2][ni], acc[mi][ni], 0, 0, 0);
        }
    }

    // epilogue: plain stores of raw partials (d_i & bias applied in reduce)
    float* P = part + (size_t)kc * NN * DD;
#pragma unroll
    for (int mi = 0; mi < 4; ++mi) {
        const int r0 = mt * 64 + mi * 16 + q * 4;
#pragma unroll
        for (int ni = 0; ni < 2; ++ni) {
            const int n = w * 32 + ni * 16 + l15;
#pragma unroll
            for (int rr = 0; rr < 4; ++rr)
                P[(size_t)(r0 + rr) * DD + n] = acc[mi][ni][rr];
        }
    }
}

// ---------------- k5: out = d_i * (p0+p1+p2+p3) + bias -------------------
__global__ __launch_bounds__(256) void reduce_kernel(const float* __restrict__ part,
                                                     const float* __restrict__ d,
                                                     const float* __restrict__ bias,
                                                     float* __restrict__ out) {
    const int idx = blockIdx.x * 256 + threadIdx.x;  // 0..524287
    const int i = idx >> 6;                          // row
    const int c4 = (idx & 63) << 2;                  // col (floats)
    const size_t off = (size_t)i * DD + c4;
    const size_t stride = (size_t)NN * DD;
    f32x4 s = *(const f32x4*)(part + off);
    s += *(const f32x4*)(part + stride + off);
    s += *(const f32x4*)(part + 2 * stride + off);
    s += *(const f32x4*)(part + 3 * stride + off);
    const float di = d[i];
    const f32x4 b = *(const f32x4*)(bias + c4);
    s = s * di + b;
    *(f32x4*)(out + off) = s;
}

extern "C" void kernel_launch(void* const* d_in, const int* in_sizes, int n_in,
                              void* d_out, int out_size, void* d_ws, size_t ws_size,
                              hipStream_t stream) {
    const float* A = (const float*)d_in[0];
    const float* X = (const float*)d_in[1];
    const float* W = (const float*)d_in[2];
    const float* bias = (const float*)d_in[3];
    const int* lp = (const int*)d_in[4];
    float* out = (float*)d_out;

    // workspace: d[8192] f32 | WT bf16[256*256] | ST_img 4MB |
    //            part f32[4*8192*256] | Abf bf16[8192*8192]  (~164.2 MB)
    float* d = (float*)d_ws;
    unsigned short* WT = (unsigned short*)((char*)d_ws + 32768);
    unsigned short* ST = (unsigned short*)((char*)d_ws + 32768 + 131072);
    float* part = (float*)((char*)d_ws + 4358144);
    unsigned short* Abf = (unsigned short*)((char*)d_ws + 37912576);
    (void)ws_size;

    rowsum_conv<<<NN / 16, 256, 0, stream>>>(A, lp, d, Abf);
    wtrans_kernel<<<16, 256, 0, stream>>>(W, WT);
    support_kernel<<<NN / 16, 256, 0, stream>>>(X, WT, d, ST);
    main_gemm<<<128 * (NN / KCHUNK), 512, 0, stream>>>(Abf, ST, part);
    reduce_kernel<<<NN * DD / 4 / 256, 256, 0, stream>>>(part, d, bias, out);
}

// Round 6
// 434.637 us; speedup vs baseline: 1.0796x; 1.0263x over previous
//
#include <hip/hip_runtime.h>

// GCNConv: out = D^-1/2 (A) D^-1/2 (X @ W) + bias,  deg = rowsum(A) + l
// N=8192, DIN=DOUT=256. A fp32 [N][N], X fp32 [N][256], W fp32 [256][256].
//
// R9 -> R10 (one variable: B L2 TRAFFIC PER OUTPUT, BM 64 -> 128):
//  * main_gemm tile BM=128, BN=256, BK=64; 256 blocks (1/CU) x 512 thr.
//    Per-wave tile 128x32 (acc 64 VGPR). Halves total B L2 reads
//    (512 MB -> 256 MB) at constant A traffic; per-CU per-iter L2 reads
//    drop 80KB/128rows -> 48KB/128rows.
//  * A: two 8KB sub-images per iter (2 gload16/thread) into a 4-deep 16KB
//    LDS ring (64 KB). Steady-state wait vmcnt(6) = A(it+1)x2 + B(it+1)x4.
//  * B image layout, k1/k2/k3/k5, partials epilogue: unchanged from R9.
// Workspace: 32KB d | 128KB WT | 4MB ST_img | 32MB partials | 128MB A_bf16.

typedef __attribute__((ext_vector_type(8))) short short8;
typedef __attribute__((ext_vector_type(4))) float f32x4;

#define NN 8192
#define DD 256
#define KCHUNK 2048
#define BK 64
#define NITER (KCHUNK / BK)

// fp32 -> bf16 RNE (no NaN guard: inputs are finite)
__device__ inline unsigned short f2bfu(float x) {
    unsigned int u = __builtin_bit_cast(unsigned int, x);
    u += 0x7fffu + ((u >> 16) & 1u);
    return (unsigned short)(u >> 16);
}
__device__ inline unsigned int f2bf2u(float x, float y) {
    return (unsigned int)f2bfu(x) | ((unsigned int)f2bfu(y) << 16);
}
__device__ inline short8 cvt8(float4 a, float4 b) {
    union { unsigned int i[4]; short8 s; } u;
    u.i[0] = f2bf2u(a.x, a.y);
    u.i[1] = f2bf2u(a.z, a.w);
    u.i[2] = f2bf2u(b.x, b.y);
    u.i[3] = f2bf2u(b.z, b.w);
    return u.s;
}

__device__ inline void gload16(const void* g, void* l) {
    __builtin_amdgcn_global_load_lds(
        (const __attribute__((address_space(1))) unsigned int*)g,
        (__attribute__((address_space(3))) unsigned int*)l, 16, 0, 0);
}

// asm global load: invisible to LLVM's waitcnt pass; retired only by our
// hand-placed s_waitcnt vmcnt(N).
#define BLOAD(dst, ptr, OFFSTR)                                        \
    asm volatile("global_load_dwordx4 %0, %1, off offset:" OFFSTR      \
                 : "=v"(dst) : "v"(ptr))

// ---------------- k1: rowsum -> d[i]; A -> bf16 swizzled tile image --------
__global__ __launch_bounds__(256) void rowsum_conv(const float* __restrict__ A,
                                                   const int* __restrict__ lp,
                                                   float* __restrict__ d,
                                                   unsigned short* __restrict__ Abf) {
    const int t = threadIdx.x;
    const int rl = t >> 4;     // row within block
    const int cg = t & 15;     // 16 threads per row
    const int i = blockIdx.x * 16 + rl;
    const int ti = i >> 6;
    const int rt = i & 63;
    const int swz = (rt & 7) << 4;

    const f32x4* Ar = (const f32x4*)(A + (size_t)i * NN);
    char* tb = (char*)Abf + (size_t)ti * 128 * 8192 + rt * 128 + ((8 * cg) ^ swz);

    float s0 = 0.f, s1 = 0.f;
#pragma unroll 4
    for (int k = 0; k < 128; ++k) {
        f32x4 v = __builtin_nontemporal_load(Ar + cg + 16 * k);  // nt: keep L3 for Abf
        s0 += v[0] + v[1];
        s1 += v[2] + v[3];
        *(uint2*)(tb + (size_t)k * 8192) =
            make_uint2(f2bf2u(v[0], v[1]), f2bf2u(v[2], v[3]));
    }
    float s = s0 + s1;
#pragma unroll
    for (int off = 8; off > 0; off >>= 1) s += __shfl_down(s, off, 16);
    if (cg == 0) {
        float deg = s + (float)(*lp);
        d[i] = deg > 0.f ? rsqrtf(deg) : 0.f;
    }
}

// ---------------- k2: W^T -> bf16 ----------------------------------------
__global__ __launch_bounds__(256) void wtrans_kernel(const float* __restrict__ W,
                                                     unsigned short* __restrict__ WT) {
    __shared__ unsigned short tile[64][65];
    const int tx = threadIdx.x & 63, ty = threadIdx.x >> 6;
    const int i0 = (blockIdx.x & 3) * 64;
    const int n0 = (blockIdx.x >> 2) * 64;
#pragma unroll
    for (int r = ty; r < 64; r += 4)
        tile[r][tx] = f2bfu(W[(size_t)(i0 + r) * DD + n0 + tx]);
    __syncthreads();
#pragma unroll
    for (int r = ty; r < 64; r += 4)
        WT[(size_t)(n0 + r) * DD + i0 + tx] = tile[tx][r];
}

// ---------------- k3: S_T image = bf16(d_j * (X@W)[j][n]) ----------------
// Output layout (fragment-ordered image, 4 MB):
//   byte = nblk32*524288 + ktile*4096 + kk2*2048 + ni*1024 + lane*16 + b
//   where n = nblk32*32 + ni*16 + (lane&15), k = ktile*64 + kk2*32 +
//   (lane>>4)*8 + b/2.  k4 reads it as 4 contiguous 1KB loads per wave-iter.
__global__ __launch_bounds__(256) void support_kernel(const float* __restrict__ X,
                                                      const unsigned short* __restrict__ WT,
                                                      const float* __restrict__ d,
                                                      unsigned short* __restrict__ ST) {
    const int j0 = blockIdx.x * 16;
    const int lane = threadIdx.x & 63;
    const int w = threadIdx.x >> 6;
    const int q = lane >> 4;
    const int l15 = lane & 15;
    const int nb = w * 64;

    f32x4 acc[4];
#pragma unroll
    for (int b = 0; b < 4; ++b) acc[b] = (f32x4)(0.f);

    const float* Xbase = X + (size_t)(j0 + l15) * DD + q * 8;
    const unsigned short* Wbase = WT + (size_t)(nb + l15) * DD + q * 8;

#pragma unroll
    for (int k0 = 0; k0 < DD; k0 += 32) {
        const float4* p = (const float4*)(Xbase + k0);
        short8 afr = cvt8(p[0], p[1]);
        short8 bfr[4];
#pragma unroll
        for (int ni = 0; ni < 4; ++ni)
            bfr[ni] = *(const short8*)(Wbase + ni * 16 * DD + k0);
#pragma unroll
        for (int ni = 0; ni < 4; ++ni)
            acc[ni] = __builtin_amdgcn_mfma_f32_16x16x32_bf16(afr, bfr[ni], acc[ni], 0, 0, 0);
    }

    const int j0r = j0 + q * 4;   // 4 consecutive k's, j0r % 4 == 0
    float dj[4];
#pragma unroll
    for (int r = 0; r < 4; ++r) dj[r] = d[j0r + r];
    // image coords from k-position (same for all ni)
    const int ktile = j0r >> 6;
    const int kk2i = (j0r >> 5) & 1;
    const int qi = (j0r >> 3) & 3;
    const int bo = (j0r & 7) * 2;  // 0 or 8
#pragma unroll
    for (int ni = 0; ni < 4; ++ni) {
        const int n = nb + ni * 16 + l15;
        unsigned int lo = f2bf2u(acc[ni][0] * dj[0], acc[ni][1] * dj[1]);
        unsigned int hi = f2bf2u(acc[ni][2] * dj[2], acc[ni][3] * dj[3]);
        char* dst = (char*)ST + (size_t)(n >> 5) * 524288 + ktile * 4096 +
                    kk2i * 2048 + ((n >> 4) & 1) * 1024 + (qi * 16 + (n & 15)) * 16 + bo;
        *(uint2*)dst = make_uint2(lo, hi);
    }
}

// ---------------- k4: partial[kc] = A_bf16 @ S_img^T ---------------------
// BM=128, BN=256, BK=64, KCHUNK=2048; 256 blocks x 512 thr (1/CU).
// Per-wave tile 128x32 (acc 64 VGPR). Per iter: [vmcnt(6); s_barrier] |
// issue A(it+2) two 8KB sub-images -> 16KB ring slot (2 gload16/thread) |
// compute(it) from LDS[it&3] + bfr[it&1] | issue B(it+2) as 4 contiguous
// 1KB loads into slot it&1. vmcnt(6) keeps {A(it+1)x2, B(it+1)x4} in flight.
__global__ __launch_bounds__(512, 2) void main_gemm(const unsigned short* __restrict__ Abf,
                                                    const unsigned short* __restrict__ ST,
                                                    float* __restrict__ part) {
    __shared__ __align__(16) unsigned short Abuf[4][8192];  // 4-deep ring, 64 KB

    const int bid = blockIdx.x;  // 0..255
    // XCD swizzle: bid%8 == XCD; 2 XCDs per kc.
    const int kc = (bid & 7) >> 1;                 // 0..3
    const int mt = ((bid >> 3) << 1) | (bid & 1);  // 0..63
    const int tid = threadIdx.x;                   // 0..511
    const int lane = tid & 63;
    const int w = tid >> 6;                        // 0..7
    const int q = lane >> 4;
    const int l15 = lane & 15;
    const int swz = (l15 & 7) << 4;

    // A image: block covers row-tiles ti0 = 2*mt, ti1 = 2*mt+1.
    // Sub-image s of k-tile kt lives at ((2*mt+s)*128 + kc*32 + kt)*8192.
    const char* Ag0 = (const char*)Abf + ((size_t)(2 * mt) * 128 + kc * NITER) * 8192 + tid * 16;
    const char* Ag1 = Ag0 + (size_t)128 * 8192;

    // B image: wave w owns nblk32 = w; tile (kc*32 + it) at 4 KB stride.
    const char* Pb = (const char*)ST + (size_t)w * 524288 + (size_t)kc * 32 * 4096 + lane * 16;

    f32x4 acc[8][2];
#pragma unroll
    for (int a = 0; a < 8; ++a)
#pragma unroll
        for (int b = 0; b < 2; ++b) acc[a][b] = (f32x4)(0.f);

    short8 bfr[2][2][2];  // [slot][kk2][ni]

    // ---- prologue: A0 (2x), B0 (4x), A1 (2x), B1 (4x) = 12 in flight
    gload16(Ag0, (char*)&Abuf[0][0] + tid * 16);
    gload16(Ag1, (char*)&Abuf[0][0] + 8192 + tid * 16);
    __builtin_amdgcn_sched_barrier(0);
    BLOAD(bfr[0][0][0], Pb, "0");
    BLOAD(bfr[0][0][1], Pb, "1024");
    BLOAD(bfr[0][1][0], Pb, "2048");
    BLOAD(bfr[0][1][1], Pb, "3072");
    __builtin_amdgcn_sched_barrier(0);
    gload16(Ag0 + 8192, (char*)&Abuf[1][0] + tid * 16);
    gload16(Ag1 + 8192, (char*)&Abuf[1][0] + 8192 + tid * 16);
    __builtin_amdgcn_sched_barrier(0);
    {
        const char* Pb1 = Pb + 4096;
        BLOAD(bfr[1][0][0], Pb1, "0");
        BLOAD(bfr[1][0][1], Pb1, "1024");
        BLOAD(bfr[1][1][0], Pb1, "2048");
        BLOAD(bfr[1][1][1], Pb1, "3072");
    }
    __builtin_amdgcn_sched_barrier(0);

    const char* AbBase = (const char*)&Abuf[0][0] + l15 * 128;
    const char* PbN = Pb + 8192;  // points at tile (it+2)

#pragma unroll 2
    for (int it = 0; it < NITER - 2; ++it) {
        // retire A(it)x2+B(it)x4; keep A(it+1)x2 + B(it+1)x4 in flight
        __asm__ __volatile__("s_waitcnt vmcnt(6)\n\ts_barrier" ::: "memory");
        __builtin_amdgcn_sched_barrier(0);

        // issue A(it+2) into ring slot (it+2)&3
        {
            const size_t go = (size_t)(it + 2) * 8192;
            char* ls = (char*)&Abuf[0][0] + (((it + 2) & 3) << 14) + tid * 16;
            gload16(Ag0 + go, ls);
            gload16(Ag1 + go, ls + 8192);
        }
        __builtin_amdgcn_sched_barrier(0);

        // compute(it): swizzled ds_read_b128 frags + register B slot it&1
        const char* Ab = AbBase + ((it & 3) << 14);
#pragma unroll
        for (int kk2 = 0; kk2 < 2; ++kk2) {
            short8 afr[8];
#pragma unroll
            for (int mi = 0; mi < 8; ++mi)
                afr[mi] = *(const short8*)(Ab + (mi >> 2) * 8192 + (mi & 3) * 2048 +
                                           ((kk2 * 64 + q * 16) ^ swz));
#pragma unroll
            for (int mi = 0; mi < 8; ++mi)
#pragma unroll
                for (int ni = 0; ni < 2; ++ni)
                    acc[mi][ni] = __builtin_amdgcn_mfma_f32_16x16x32_bf16(
                        afr[mi], bfr[it & 1][kk2][ni], acc[mi][ni], 0, 0, 0);
        }
        __builtin_amdgcn_sched_barrier(0);

        // issue B(it+2) into slot it&1 (all consuming MFMAs already issued)
        BLOAD(bfr[it & 1][0][0], PbN, "0");
        BLOAD(bfr[it & 1][0][1], PbN, "1024");
        BLOAD(bfr[it & 1][1][0], PbN, "2048");
        BLOAD(bfr[it & 1][1][1], PbN, "3072");
        PbN += 4096;
        __builtin_amdgcn_sched_barrier(0);
    }

    // ---- peel it = NITER-2 (ring 2, slot 0)
    __asm__ __volatile__("s_waitcnt vmcnt(6)\n\ts_barrier" ::: "memory");
    __builtin_amdgcn_sched_barrier(0);
    {
        const char* Ab = AbBase + (((NITER - 2) & 3) << 14);
#pragma unroll
        for (int kk2 = 0; kk2 < 2; ++kk2) {
            short8 afr[8];
#pragma unroll
            for (int mi = 0; mi < 8; ++mi)
                afr[mi] = *(const short8*)(Ab + (mi >> 2) * 8192 + (mi & 3) * 2048 +
                                           ((kk2 * 64 + q * 16) ^ swz));
#pragma unroll
            for (int mi = 0; mi < 8; ++mi)
#pragma unroll
                for (int ni = 0; ni < 2; ++ni)
                    acc[mi][ni] = __builtin_amdgcn_mfma_f32_16x16x32_bf16(
                        afr[mi], bfr[0][kk2][ni], acc[mi][ni], 0, 0, 0);
        }
    }
    // ---- peel it = NITER-1 (ring 3, slot 1)
    __asm__ __volatile__("s_waitcnt vmcnt(0)\n\ts_barrier" ::: "memory");
    __builtin_amdgcn_sched_barrier(0);
    {
        const char* Ab = AbBase + (((NITER - 1) & 3) << 14);
#pragma unroll
        for (int kk2 = 0; kk2 < 2; ++kk2) {
            short8 afr[8];
#pragma unroll
            for (int mi = 0; mi < 8; ++mi)
                afr[mi] = *(const short8*)(Ab + (mi >> 2) * 8192 + (mi & 3) * 2048 +
                                           ((kk2 * 64 + q * 16) ^ swz));
#pragma unroll
            for (int mi = 0; mi < 8; ++mi)
#pragma unroll
                for (int ni = 0; ni < 2; ++ni)
                    acc[mi][ni] = __builtin_amdgcn_mfma_f32_16x16x32_bf16(
                        afr[mi], bfr[1][kk2][ni], acc[mi][ni], 0, 0, 0);
        }
    }

    // epilogue: plain stores of raw partials (d_i & bias applied in reduce)
    float* P = part + (size_t)kc * NN * DD;
#pragma unroll
    for (int mi = 0; mi < 8; ++mi) {
        const int r0 = mt * 128 + mi * 16 + q * 4;
#pragma unroll
        for (int ni = 0; ni < 2; ++ni) {
            const int n = w * 32 + ni * 16 + l15;
#pragma unroll
            for (int rr = 0; rr < 4; ++rr)
                P[(size_t)(r0 + rr) * DD + n] = acc[mi][ni][rr];
        }
    }
}

// ---------------- k5: out = d_i * (p0+p1+p2+p3) + bias -------------------
__global__ __launch_bounds__(256) void reduce_kernel(const float* __restrict__ part,
                                                     const float* __restrict__ d,
                                                     const float* __restrict__ bias,
                                                     float* __restrict__ out) {
    const int idx = blockIdx.x * 256 + threadIdx.x;  // 0..524287
    const int i = idx >> 6;                          // row
    const int c4 = (idx & 63) << 2;                  // col (floats)
    const size_t off = (size_t)i * DD + c4;
    const size_t stride = (size_t)NN * DD;
    f32x4 s = *(const f32x4*)(part + off);
    s += *(const f32x4*)(part + stride + off);
    s += *(const f32x4*)(part + 2 * stride + off);
    s += *(const f32x4*)(part + 3 * stride + off);
    const float di = d[i];
    const f32x4 b = *(const f32x4*)(bias + c4);
    s = s * di + b;
    *(f32x4*)(out + off) = s;
}

extern "C" void kernel_launch(void* const* d_in, const int* in_sizes, int n_in,
                              void* d_out, int out_size, void* d_ws, size_t ws_size,
                              hipStream_t stream) {
    const float* A = (const float*)d_in[0];
    const float* X = (const float*)d_in[1];
    const float* W = (const float*)d_in[2];
    const float* bias = (const float*)d_in[3];
    const int* lp = (const int*)d_in[4];
    float* out = (float*)d_out;

    // workspace: d[8192] f32 | WT bf16[256*256] | ST_img 4MB |
    //            part f32[4*8192*256] | Abf bf16[8192*8192]  (~164.2 MB)
    float* d = (float*)d_ws;
    unsigned short* WT = (unsigned short*)((char*)d_ws + 32768);
    unsigned short* ST = (unsigned short*)((char*)d_ws + 32768 + 131072);
    float* part = (float*)((char*)d_ws + 4358144);
    unsigned short* Abf = (unsigned short*)((char*)d_ws + 37912576);
    (void)ws_size;

    rowsum_conv<<<NN / 16, 256, 0, stream>>>(A, lp, d, Abf);
    wtrans_kernel<<<16, 256, 0, stream>>>(W, WT);
    support_kernel<<<NN / 16, 256, 0, stream>>>(X, WT, d, ST);
    main_gemm<<<256, 512, 0, stream>>>(Abf, ST, part);
    reduce_kernel<<<NN * DD / 4 / 256, 256, 0, stream>>>(part, d, bias, out);
}